// Round 5
// baseline (988.288 us; speedup 1.0000x reference)
//
#include <hip/hip_runtime.h>

typedef __bf16 bf16_t;
typedef bf16_t bf16x4 __attribute__((ext_vector_type(4)));
typedef bf16_t bf16x8 __attribute__((ext_vector_type(8)));
typedef float floatx4 __attribute__((ext_vector_type(4)));

#define F_INq 64
#define F_OUTq 128
#define PERIODSq 12
#define XROW (F_INq * PERIODSq) /* 768 */

// ---------------- degree / CSR build ----------------
__global__ __launch_bounds__(256) void k_init(float* deg, int* counts, int N) {
  int i = blockIdx.x * 256 + threadIdx.x;
  if (i < N) { deg[i] = 1.0f; counts[i] = 0; }  // self-loop weight 1
}

__global__ __launch_bounds__(256) void k_accum(const int* __restrict__ ei, const float* __restrict__ ew,
                                               float* deg, int* counts, int E) {
  int e = blockIdx.x * 256 + threadIdx.x;
  if (e < E) {
    int c = ei[E + e];  // target
    atomicAdd(&deg[c], ew[e]);
    atomicAdd(&counts[c], 1);
  }
}

__global__ __launch_bounds__(256) void k_dinv(float* deg, int N) {
  int i = blockIdx.x * 256 + threadIdx.x;
  if (i < N) { float d = deg[i]; deg[i] = d > 0.0f ? rsqrtf(d) : 0.0f; }
}

__global__ __launch_bounds__(1024) void k_scan(const int* __restrict__ counts, int* __restrict__ offs,
                                               int* __restrict__ cursor, int N) {
  __shared__ int sd[1024];
  int t = threadIdx.x;
  int CH = (N + 1023) >> 10;
  int base = t * CH;
  int sum = 0;
  for (int i = 0; i < CH; ++i) { int idx = base + i; if (idx < N) sum += counts[idx]; }
  sd[t] = sum;
  __syncthreads();
  for (int off = 1; off < 1024; off <<= 1) {
    int v = (t >= off) ? sd[t - off] : 0;
    __syncthreads();
    sd[t] += v;
    __syncthreads();
  }
  int run = sd[t] - sum;  // exclusive prefix
  for (int i = 0; i < CH; ++i) {
    int idx = base + i;
    if (idx < N) { offs[idx] = run; cursor[idx] = run; run += counts[idx]; }
  }
  if (t == 1023) offs[N] = sd[1023];
}

__global__ __launch_bounds__(256) void k_scatter(const int* __restrict__ ei, const float* __restrict__ ew,
                                                 const float* __restrict__ dinv, int* cursor,
                                                 int* __restrict__ csr_src, float* __restrict__ csr_nrm, int E) {
  int e = blockIdx.x * 256 + threadIdx.x;
  if (e < E) {
    int r = ei[e], c = ei[E + e];
    int p = atomicAdd(&cursor[c], 1);
    csr_src[p] = r;
    csr_nrm[p] = dinv[r] * ew[e] * dinv[c];
  }
}

// ---------------- weight precompute: W_bigT[512][192], b_comb[512], probs[12] ----------------
__global__ __launch_bounds__(256) void k_prew(
    const float* __restrict__ Wxi, const float* __restrict__ Whi,
    const float* __restrict__ Wxf, const float* __restrict__ Whf,
    const float* __restrict__ Wxc, const float* __restrict__ Whc,
    const float* __restrict__ Wxo, const float* __restrict__ Who,
    const float* __restrict__ bxi, const float* __restrict__ bhi,
    const float* __restrict__ bxf, const float* __restrict__ bhf,
    const float* __restrict__ bxc, const float* __restrict__ bhc,
    const float* __restrict__ bxo, const float* __restrict__ bho,
    const float* __restrict__ att,
    bf16_t* __restrict__ WbT, float* __restrict__ bcomb, float* __restrict__ probs) {
  const int WT = 512 * 192;
  int gid = blockIdx.x * 256 + threadIdx.x;
  if (gid < WT) {
    int col = gid / 192, k = gid % 192;
    int g = col >> 7, j = col & 127;
    const float* Wx = g == 0 ? Wxi : g == 1 ? Wxf : g == 2 ? Wxc : Wxo;
    const float* Wh = g == 0 ? Whi : g == 1 ? Whf : g == 2 ? Whc : Who;
    float s;
    if (k < 64) {
      s = 0.0f;
      for (int kk = 0; kk < 128; ++kk) s += Wx[k * 128 + kk] * Wh[kk * 128 + j];
    } else {
      s = Wh[(k + 64) * 128 + j];
    }
    WbT[(size_t)col * 192 + k] = (bf16_t)s;
  } else if (gid < WT + 512) {
    int cc = gid - WT;
    int g = cc >> 7, j = cc & 127;
    const float* bx = g == 0 ? bxi : g == 1 ? bxf : g == 2 ? bxc : bxo;
    const float* bh = g == 0 ? bhi : g == 1 ? bhf : g == 2 ? bhc : bho;
    const float* Wh = g == 0 ? Whi : g == 1 ? Whf : g == 2 ? Whc : Who;
    float s = bh[j];
    for (int kk = 0; kk < 128; ++kk) s += bx[kk] * Wh[kk * 128 + j];
    bcomb[cc] = s;
  } else if (gid == WT + 512) {
    float m = att[0];
    for (int i = 1; i < PERIODSq; ++i) m = fmaxf(m, att[i]);
    float e[PERIODSq], s = 0.0f;
    for (int i = 0; i < PERIODSq; ++i) { e[i] = __expf(att[i] - m); s += e[i]; }
    for (int i = 0; i < PERIODSq; ++i) probs[i] = e[i] / s;
  }
}

// ---------------- X transpose/convert: X[n][f][t] fp32 -> Xb[n][t*64+f] bf16 ----------------
__global__ __launch_bounds__(192) void k_xpose(const float* __restrict__ X, bf16_t* __restrict__ Xb) {
  __shared__ float lds[XROW];
  const int n = blockIdx.x, tid = threadIdx.x;
  const float4* Xr = (const float4*)(X + (size_t)n * XROW);
  float4 v = Xr[tid];
  lds[tid * 4 + 0] = v.x;
  lds[tid * 4 + 1] = v.y;
  lds[tid * 4 + 2] = v.z;
  lds[tid * 4 + 3] = v.w;
  __syncthreads();
  const int o = tid * 4;
  bf16x4 r;
#pragma unroll
  for (int k = 0; k < 4; ++k) {
    int oo = o + k;
    int tt = oo >> 6, f = oo & 63;
    r[k] = (bf16_t)lds[f * PERIODSq + tt];
  }
  *(bf16x4*)(Xb + (size_t)n * XROW + o) = r;
}

// ---------------- aggregation (bf16 gather): Xagg[t][n][64] = A_norm @ X ----------------
// one wave per node; 8-edge software pipeline: 24 gathers in flight (L2/L3 latency-bound)
__global__ __launch_bounds__(256) void k_agg2(const bf16_t* __restrict__ Xb, const int* __restrict__ csr_src,
                                              const float* __restrict__ csr_nrm, const int* __restrict__ offs,
                                              const float* __restrict__ dinv, bf16_t* __restrict__ Xagg, int N) {
  const int node = blockIdx.x * 4 + (threadIdx.x >> 6);
  const int lane = threadIdx.x & 63;
  const int s0 = offs[node], s1 = offs[node + 1];
  floatx4 a0 = {0.f, 0.f, 0.f, 0.f}, a1 = a0, a2 = a0;
  int e = s0;
  for (; e + 8 <= s1; e += 8) {
    bf16x4 v[8][3];
    float nn[8];
#pragma unroll
    for (int u = 0; u < 8; ++u) {
      int s = csr_src[e + u];
      nn[u] = csr_nrm[e + u];
      const bf16x4* xp = (const bf16x4*)(Xb + (size_t)s * XROW) + lane;
      v[u][0] = xp[0]; v[u][1] = xp[64]; v[u][2] = xp[128];
    }
#pragma unroll
    for (int u = 0; u < 8; ++u) {
#pragma unroll
      for (int k = 0; k < 4; ++k) {
        a0[k] += nn[u] * (float)v[u][0][k];
        a1[k] += nn[u] * (float)v[u][1][k];
        a2[k] += nn[u] * (float)v[u][2][k];
      }
    }
  }
  for (; e < s1; ++e) {
    int s = csr_src[e];
    float nr = csr_nrm[e];
    const bf16x4* xp = (const bf16x4*)(Xb + (size_t)s * XROW) + lane;
    bf16x4 v0 = xp[0], v1 = xp[64], v2 = xp[128];
#pragma unroll
    for (int k = 0; k < 4; ++k) {
      a0[k] += nr * (float)v0[k];
      a1[k] += nr * (float)v1[k];
      a2[k] += nr * (float)v2[k];
    }
  }
  float dc = dinv[node];
  float self = dc * dc;
  const bf16x4* xc = (const bf16x4*)(Xb + (size_t)node * XROW) + lane;
  {
    bf16x4 v0 = xc[0], v1 = xc[64], v2 = xc[128];
#pragma unroll
    for (int k = 0; k < 4; ++k) {
      a0[k] += self * (float)v0[k];
      a1[k] += self * (float)v1[k];
      a2[k] += self * (float)v2[k];
    }
  }
  const int f4 = lane & 15, tq = lane >> 4;
  floatx4 accs[3] = {a0, a1, a2};
#pragma unroll
  for (int j = 0; j < 3; ++j) {
    int tt = tq + 4 * j;
    bf16x4 r;
#pragma unroll
    for (int k = 0; k < 4; ++k) r[k] = (bf16_t)accs[j][k];
    *(bf16x4*)(Xagg + ((size_t)tt * N + node) * 64 + f4 * 4) = r;
  }
}

// ---------------- fallback aggregation (fp32 gather, used only if ws too small) ----------------
__global__ __launch_bounds__(256) void k_agg(const float* __restrict__ X, const int* __restrict__ csr_src,
                                             const float* __restrict__ csr_nrm, const int* __restrict__ offs,
                                             const float* __restrict__ dinv, bf16_t* __restrict__ Xagg, int N) {
  int c = blockIdx.x;
  int tid = threadIdx.x;
  int s0 = offs[c], s1 = offs[c + 1];
  const int i0 = tid, i1 = tid + 256, i2 = tid + 512;
  float a0 = 0.f, a1 = 0.f, a2 = 0.f;
  for (int e = s0; e < s1; ++e) {
    int s = csr_src[e];
    float nr = csr_nrm[e];
    const float* xp = X + (size_t)s * XROW;
    a0 += nr * xp[i0]; a1 += nr * xp[i1]; a2 += nr * xp[i2];
  }
  float dc = dinv[c];
  float self = dc * dc;
  const float* xc = X + (size_t)c * XROW;
  a0 += self * xc[i0]; a1 += self * xc[i1]; a2 += self * xc[i2];
  __shared__ float lds[XROW];
  lds[i0] = a0; lds[i1] = a1; lds[i2] = a2;
  __syncthreads();
  for (int o = tid; o < XROW; o += 256) {
    int tt = o >> 6, f = o & 63;
    Xagg[(size_t)tt * N * 64 + (size_t)c * 64 + f] = (bf16_t)lds[f * PERIODSq + tt];
  }
}

// ---------------- persistent fused LSTM, W-stationary, slim registers ----------------
// Block: 16 rows, 512 thr = 8 waves, 2 blocks/CU target. Wave w holds W for its 16 cols x
// 4 gates in 96 VGPRs. X B-frags read DIRECT from global (coalesced 128B rows, no LDS).
// H double-buffered in LDS (pitch 134 bf16 = 67 dw == 3 mod 32 -> <=2-way banks, free).
// bias/probs/Hacc live in LDS to keep VGPR <= 128 (4 waves/SIMD => 2 blocks/CU).
#define HS_P 134
__global__ __launch_bounds__(512, 4) void k_gate_all(const bf16_t* __restrict__ Xagg,
                                                     const bf16_t* __restrict__ WbT,
                                                     const float* __restrict__ bcomb,
                                                     const float* __restrict__ probs,
                                                     float* __restrict__ out, int N) {
  __shared__ bf16_t Hs[2][16][HS_P];
  __shared__ float HaS[512 * 4];
  __shared__ float biasS[512];
  __shared__ float probsS[16];
  const int tid = threadIdx.x;
  const int lane = tid & 63, w = tid >> 6;
  const int q = lane >> 4, c0 = lane & 15;
  const int n0 = blockIdx.x * 16;

  biasS[tid] = bcomb[tid];
  if (tid < PERIODSq) probsS[tid] = probs[tid];
  for (int i = tid; i < 16 * HS_P / 2; i += 512) ((unsigned int*)&Hs[0][0][0])[i] = 0u;
  *(floatx4*)&HaS[tid * 4] = (floatx4){0.f, 0.f, 0.f, 0.f};

  // stationary W fragments: col = (g*8+w)*16 + c0, k-chunk ks*32 + q*8
  bf16x8 Wf[4][6];
#pragma unroll
  for (int g = 0; g < 4; ++g) {
    const bf16_t* wp = WbT + (size_t)((g * 8 + w) * 16 + c0) * 192;
#pragma unroll
    for (int ks = 0; ks < 6; ++ks) Wf[g][ks] = *(const bf16x8*)(wp + ks * 32 + q * 8);
  }
  floatx4 Cst = {0.f, 0.f, 0.f, 0.f};
  __syncthreads();

  const float NL2E = -1.44269504f;   // -log2(e)
  const float T2L2E = 2.88539008f;   // 2*log2(e)
  const bf16_t* Xrow = Xagg + (size_t)(n0 + c0) * 64 + q * 8;

  for (int t = 0; t < PERIODSq; ++t) {
    const int cur = t & 1, nxt = cur ^ 1;
    // X-part B-fragments straight from global (long-latency; H-MFMAs below overlap them)
    const bf16_t* Xt = Xrow + (size_t)t * N * 64;
    bf16x8 X0 = *(const bf16x8*)(Xt);
    bf16x8 X1 = *(const bf16x8*)(Xt + 32);
    floatx4 acc[4];
#pragma unroll
    for (int g = 0; g < 4; ++g) acc[g] = (floatx4){0.f, 0.f, 0.f, 0.f};
#pragma unroll
    for (int ks = 0; ks < 4; ++ks) {
      bf16x8 B = *(const bf16x8*)&Hs[cur][c0][ks * 32 + q * 8];
#pragma unroll
      for (int g = 0; g < 4; ++g)
        acc[g] = __builtin_amdgcn_mfma_f32_16x16x32_bf16(Wf[g][ks + 2], B, acc[g], 0, 0, 0);
    }
#pragma unroll
    for (int g = 0; g < 4; ++g)
      acc[g] = __builtin_amdgcn_mfma_f32_16x16x32_bf16(Wf[g][0], X0, acc[g], 0, 0, 0);
#pragma unroll
    for (int g = 0; g < 4; ++g)
      acc[g] = __builtin_amdgcn_mfma_f32_16x16x32_bf16(Wf[g][1], X1, acc[g], 0, 0, 0);
    // bias add (broadcast LDS reads; transient registers)
#pragma unroll
    for (int g = 0; g < 4; ++g) {
      floatx4 bv = *(const floatx4*)&biasS[g * 128 + w * 16 + q * 4];
      acc[g] += bv;
    }
    const float pt = probsS[t];
    floatx4 ha = *(const floatx4*)&HaS[tid * 4];
    bf16x4 hv;
#pragma unroll
    for (int r = 0; r < 4; ++r) {
      float I = __builtin_amdgcn_rcpf(1.0f + __builtin_amdgcn_exp2f(acc[0][r] * NL2E));
      float F = __builtin_amdgcn_rcpf(1.0f + __builtin_amdgcn_exp2f(acc[1][r] * NL2E));
      float Ct = fmaf(-2.0f, __builtin_amdgcn_rcpf(1.0f + __builtin_amdgcn_exp2f(acc[2][r] * T2L2E)), 1.0f);
      float O = __builtin_amdgcn_rcpf(1.0f + __builtin_amdgcn_exp2f(acc[3][r] * NL2E));
      float Cn = fmaf(F, Cst[r], I * Ct);
      Cst[r] = Cn;
      float tC = fmaf(-2.0f, __builtin_amdgcn_rcpf(1.0f + __builtin_amdgcn_exp2f(Cn * T2L2E)), 1.0f);
      float Hn = O * tC;
      ha[r] = fmaf(pt, Hn, ha[r]);
      hv[r] = (bf16_t)Hn;
    }
    *(floatx4*)&HaS[tid * 4] = ha;
    *(bf16x4*)&Hs[nxt][c0][w * 16 + q * 4] = hv;
    __syncthreads();
  }
  floatx4 ha = *(const floatx4*)&HaS[tid * 4];
  const int row = n0 + c0;
  *(floatx4*)(out + (size_t)row * 128 + w * 16 + q * 4) = ha;
}

// ---------------- host ----------------
extern "C" void kernel_launch(void* const* d_in, const int* in_sizes, int n_in,
                              void* d_out, int out_size, void* d_ws, size_t ws_size,
                              hipStream_t stream) {
  const float* X = (const float*)d_in[0];
  const int* ei = (const int*)d_in[1];
  const float* ew = (const float*)d_in[2];
  const float* att = (const float*)d_in[3];
  const float* Wxi = (const float*)d_in[4];
  const float* bxi = (const float*)d_in[5];
  const float* Whi = (const float*)d_in[6];
  const float* bhi = (const float*)d_in[7];
  const float* Wxf = (const float*)d_in[8];
  const float* bxf = (const float*)d_in[9];
  const float* Whf = (const float*)d_in[10];
  const float* bhf = (const float*)d_in[11];
  const float* Wxc = (const float*)d_in[12];
  const float* bxc = (const float*)d_in[13];
  const float* Whc = (const float*)d_in[14];
  const float* bhc = (const float*)d_in[15];
  const float* Wxo = (const float*)d_in[16];
  const float* bxo = (const float*)d_in[17];
  const float* Who = (const float*)d_in[18];
  const float* bho = (const float*)d_in[19];
  float* out = (float*)d_out;

  const int N = in_sizes[0] / XROW;  // 40000
  const int E = in_sizes[2];         // 640000

  char* base = (char*)d_ws;
  size_t off = 0;
  auto carve = [&](size_t bytes) {
    char* r = base + off;
    off += (bytes + 255) & ~(size_t)255;
    return (void*)r;
  };
  float* deg = (float*)carve((size_t)N * 4);  // becomes dinv in-place
  int* counts = (int*)carve((size_t)N * 4);
  int* offs = (int*)carve((size_t)(N + 1) * 4);
  int* cursor = (int*)carve((size_t)(N + 1) * 4);
  int* csr_src = (int*)carve((size_t)E * 4);
  float* csr_nrm = (float*)carve((size_t)E * 4);
  bf16_t* WbT = (bf16_t*)carve((size_t)512 * 192 * 2);
  float* bcomb = (float*)carve(512 * 4);
  float* probs = (float*)carve(64);
  bf16_t* Xagg = (bf16_t*)carve((size_t)PERIODSq * N * 64 * 2);
  bf16_t* Xb = (bf16_t*)carve((size_t)N * XROW * 2);
  const bool use_bf16 = (off <= ws_size);  // fall back to fp32 gather if ws too small

  k_init<<<(N + 255) / 256, 256, 0, stream>>>(deg, counts, N);
  k_accum<<<(E + 255) / 256, 256, 0, stream>>>(ei, ew, deg, counts, E);
  k_dinv<<<(N + 255) / 256, 256, 0, stream>>>(deg, N);
  k_scan<<<1, 1024, 0, stream>>>(counts, offs, cursor, N);
  k_scatter<<<(E + 255) / 256, 256, 0, stream>>>(ei, ew, deg, cursor, csr_src, csr_nrm, E);
  k_prew<<<(512 * 192 + 512 + 1 + 255) / 256, 256, 0, stream>>>(
      Wxi, Whi, Wxf, Whf, Wxc, Whc, Wxo, Who,
      bxi, bhi, bxf, bhf, bxc, bhc, bxo, bho, att, WbT, bcomb, probs);

  if (use_bf16) {
    k_xpose<<<N, 192, 0, stream>>>(X, Xb);
    k_agg2<<<N / 4, 256, 0, stream>>>(Xb, csr_src, csr_nrm, offs, deg, Xagg, N);
  } else {
    k_agg<<<N, 256, 0, stream>>>(X, csr_src, csr_nrm, offs, deg, Xagg, N);
  }

  k_gate_all<<<N / 16, 512, 0, stream>>>(Xagg, WbT, bcomb, probs, out, N);
}

// Round 6
// 747.805 us; speedup vs baseline: 1.3216x; 1.3216x over previous
//
#include <hip/hip_runtime.h>

typedef __bf16 bf16_t;
typedef bf16_t bf16x4 __attribute__((ext_vector_type(4)));
typedef bf16_t bf16x8 __attribute__((ext_vector_type(8)));
typedef float floatx4 __attribute__((ext_vector_type(4)));

#define F_INq 64
#define F_OUTq 128
#define PERIODSq 12
#define XROW (F_INq * PERIODSq) /* 768 */

// ---------------- degree / CSR build ----------------
__global__ __launch_bounds__(256) void k_init(float* deg, int* counts, int N) {
  int i = blockIdx.x * 256 + threadIdx.x;
  if (i < N) { deg[i] = 1.0f; counts[i] = 0; }  // self-loop weight 1
}

__global__ __launch_bounds__(256) void k_accum(const int* __restrict__ ei, const float* __restrict__ ew,
                                               float* deg, int* counts, int E) {
  int e = blockIdx.x * 256 + threadIdx.x;
  if (e < E) {
    int c = ei[E + e];  // target
    atomicAdd(&deg[c], ew[e]);
    atomicAdd(&counts[c], 1);
  }
}

__global__ __launch_bounds__(256) void k_dinv(float* deg, int N) {
  int i = blockIdx.x * 256 + threadIdx.x;
  if (i < N) { float d = deg[i]; deg[i] = d > 0.0f ? rsqrtf(d) : 0.0f; }
}

__global__ __launch_bounds__(1024) void k_scan(const int* __restrict__ counts, int* __restrict__ offs,
                                               int* __restrict__ cursor, int N) {
  __shared__ int sd[1024];
  int t = threadIdx.x;
  int CH = (N + 1023) >> 10;
  int base = t * CH;
  int sum = 0;
  for (int i = 0; i < CH; ++i) { int idx = base + i; if (idx < N) sum += counts[idx]; }
  sd[t] = sum;
  __syncthreads();
  for (int off = 1; off < 1024; off <<= 1) {
    int v = (t >= off) ? sd[t - off] : 0;
    __syncthreads();
    sd[t] += v;
    __syncthreads();
  }
  int run = sd[t] - sum;  // exclusive prefix
  for (int i = 0; i < CH; ++i) {
    int idx = base + i;
    if (idx < N) { offs[idx] = run; cursor[idx] = run; run += counts[idx]; }
  }
  if (t == 1023) offs[N] = sd[1023];
}

__global__ __launch_bounds__(256) void k_scatter(const int* __restrict__ ei, const float* __restrict__ ew,
                                                 const float* __restrict__ dinv, int* cursor,
                                                 int* __restrict__ csr_src, float* __restrict__ csr_nrm, int E) {
  int e = blockIdx.x * 256 + threadIdx.x;
  if (e < E) {
    int r = ei[e], c = ei[E + e];
    int p = atomicAdd(&cursor[c], 1);
    csr_src[p] = r;
    csr_nrm[p] = dinv[r] * ew[e] * dinv[c];
  }
}

// ---------------- weight precompute: W_bigT[512][192], b_comb[512], probs[12] ----------------
__global__ __launch_bounds__(256) void k_prew(
    const float* __restrict__ Wxi, const float* __restrict__ Whi,
    const float* __restrict__ Wxf, const float* __restrict__ Whf,
    const float* __restrict__ Wxc, const float* __restrict__ Whc,
    const float* __restrict__ Wxo, const float* __restrict__ Who,
    const float* __restrict__ bxi, const float* __restrict__ bhi,
    const float* __restrict__ bxf, const float* __restrict__ bhf,
    const float* __restrict__ bxc, const float* __restrict__ bhc,
    const float* __restrict__ bxo, const float* __restrict__ bho,
    const float* __restrict__ att,
    bf16_t* __restrict__ WbT, float* __restrict__ bcomb, float* __restrict__ probs) {
  const int WT = 512 * 192;
  int gid = blockIdx.x * 256 + threadIdx.x;
  if (gid < WT) {
    int col = gid / 192, k = gid % 192;
    int g = col >> 7, j = col & 127;
    const float* Wx = g == 0 ? Wxi : g == 1 ? Wxf : g == 2 ? Wxc : Wxo;
    const float* Wh = g == 0 ? Whi : g == 1 ? Whf : g == 2 ? Whc : Who;
    float s;
    if (k < 64) {
      s = 0.0f;
      for (int kk = 0; kk < 128; ++kk) s += Wx[k * 128 + kk] * Wh[kk * 128 + j];
    } else {
      s = Wh[(k + 64) * 128 + j];
    }
    WbT[(size_t)col * 192 + k] = (bf16_t)s;
  } else if (gid < WT + 512) {
    int cc = gid - WT;
    int g = cc >> 7, j = cc & 127;
    const float* bx = g == 0 ? bxi : g == 1 ? bxf : g == 2 ? bxc : bxo;
    const float* bh = g == 0 ? bhi : g == 1 ? bhf : g == 2 ? bhc : bho;
    const float* Wh = g == 0 ? Whi : g == 1 ? Whf : g == 2 ? Whc : Who;
    float s = bh[j];
    for (int kk = 0; kk < 128; ++kk) s += bx[kk] * Wh[kk * 128 + j];
    bcomb[cc] = s;
  } else if (gid == WT + 512) {
    float m = att[0];
    for (int i = 1; i < PERIODSq; ++i) m = fmaxf(m, att[i]);
    float e[PERIODSq], s = 0.0f;
    for (int i = 0; i < PERIODSq; ++i) { e[i] = __expf(att[i] - m); s += e[i]; }
    for (int i = 0; i < PERIODSq; ++i) probs[i] = e[i] / s;
  }
}

// ---------------- X transpose/convert: X[n][f][t] fp32 -> Xb[n][t*64+f] bf16 ----------------
__global__ __launch_bounds__(192) void k_xpose(const float* __restrict__ X, bf16_t* __restrict__ Xb) {
  __shared__ float lds[XROW];
  const int n = blockIdx.x, tid = threadIdx.x;
  const float4* Xr = (const float4*)(X + (size_t)n * XROW);
  float4 v = Xr[tid];
  lds[tid * 4 + 0] = v.x;
  lds[tid * 4 + 1] = v.y;
  lds[tid * 4 + 2] = v.z;
  lds[tid * 4 + 3] = v.w;
  __syncthreads();
  const int o = tid * 4;
  bf16x4 r;
#pragma unroll
  for (int k = 0; k < 4; ++k) {
    int oo = o + k;
    int tt = oo >> 6, f = oo & 63;
    r[k] = (bf16_t)lds[f * PERIODSq + tt];
  }
  *(bf16x4*)(Xb + (size_t)n * XROW + o) = r;
}

// ---------------- aggregation (bf16 gather): Xagg[t][n][64] = A_norm @ X ----------------
// one wave per node; 8-edge software pipeline: 24 gathers in flight (L2/L3 latency-bound)
__global__ __launch_bounds__(256) void k_agg2(const bf16_t* __restrict__ Xb, const int* __restrict__ csr_src,
                                              const float* __restrict__ csr_nrm, const int* __restrict__ offs,
                                              const float* __restrict__ dinv, bf16_t* __restrict__ Xagg, int N) {
  const int node = blockIdx.x * 4 + (threadIdx.x >> 6);
  const int lane = threadIdx.x & 63;
  const int s0 = offs[node], s1 = offs[node + 1];
  floatx4 a0 = {0.f, 0.f, 0.f, 0.f}, a1 = a0, a2 = a0;
  int e = s0;
  for (; e + 8 <= s1; e += 8) {
    bf16x4 v[8][3];
    float nn[8];
#pragma unroll
    for (int u = 0; u < 8; ++u) {
      int s = csr_src[e + u];
      nn[u] = csr_nrm[e + u];
      const bf16x4* xp = (const bf16x4*)(Xb + (size_t)s * XROW) + lane;
      v[u][0] = xp[0]; v[u][1] = xp[64]; v[u][2] = xp[128];
    }
#pragma unroll
    for (int u = 0; u < 8; ++u) {
#pragma unroll
      for (int k = 0; k < 4; ++k) {
        a0[k] += nn[u] * (float)v[u][0][k];
        a1[k] += nn[u] * (float)v[u][1][k];
        a2[k] += nn[u] * (float)v[u][2][k];
      }
    }
  }
  for (; e < s1; ++e) {
    int s = csr_src[e];
    float nr = csr_nrm[e];
    const bf16x4* xp = (const bf16x4*)(Xb + (size_t)s * XROW) + lane;
    bf16x4 v0 = xp[0], v1 = xp[64], v2 = xp[128];
#pragma unroll
    for (int k = 0; k < 4; ++k) {
      a0[k] += nr * (float)v0[k];
      a1[k] += nr * (float)v1[k];
      a2[k] += nr * (float)v2[k];
    }
  }
  float dc = dinv[node];
  float self = dc * dc;
  const bf16x4* xc = (const bf16x4*)(Xb + (size_t)node * XROW) + lane;
  {
    bf16x4 v0 = xc[0], v1 = xc[64], v2 = xc[128];
#pragma unroll
    for (int k = 0; k < 4; ++k) {
      a0[k] += self * (float)v0[k];
      a1[k] += self * (float)v1[k];
      a2[k] += self * (float)v2[k];
    }
  }
  const int f4 = lane & 15, tq = lane >> 4;
  floatx4 accs[3] = {a0, a1, a2};
#pragma unroll
  for (int j = 0; j < 3; ++j) {
    int tt = tq + 4 * j;
    bf16x4 r;
#pragma unroll
    for (int k = 0; k < 4; ++k) r[k] = (bf16_t)accs[j][k];
    *(bf16x4*)(Xagg + ((size_t)tt * N + node) * 64 + f4 * 4) = r;
  }
}

// ---------------- fallback aggregation (fp32 gather, used only if ws too small) ----------------
__global__ __launch_bounds__(256) void k_agg(const float* __restrict__ X, const int* __restrict__ csr_src,
                                             const float* __restrict__ csr_nrm, const int* __restrict__ offs,
                                             const float* __restrict__ dinv, bf16_t* __restrict__ Xagg, int N) {
  int c = blockIdx.x;
  int tid = threadIdx.x;
  int s0 = offs[c], s1 = offs[c + 1];
  const int i0 = tid, i1 = tid + 256, i2 = tid + 512;
  float a0 = 0.f, a1 = 0.f, a2 = 0.f;
  for (int e = s0; e < s1; ++e) {
    int s = csr_src[e];
    float nr = csr_nrm[e];
    const float* xp = X + (size_t)s * XROW;
    a0 += nr * xp[i0]; a1 += nr * xp[i1]; a2 += nr * xp[i2];
  }
  float dc = dinv[c];
  float self = dc * dc;
  const float* xc = X + (size_t)c * XROW;
  a0 += self * xc[i0]; a1 += self * xc[i1]; a2 += self * xc[i2];
  __shared__ float lds[XROW];
  lds[i0] = a0; lds[i1] = a1; lds[i2] = a2;
  __syncthreads();
  for (int o = tid; o < XROW; o += 256) {
    int tt = o >> 6, f = o & 63;
    Xagg[(size_t)tt * N * 64 + (size_t)c * 64 + f] = (bf16_t)lds[f * PERIODSq + tt];
  }
}

// ---------------- persistent fused LSTM, W-stationary, fast epilogue ----------------
// Round-3 structure: 32 rows/block, 512 thr = 8 gate-complete waves, 1 block/CU (accepted —
// round 5 proved Wf(96)+acc can't fit under the 128-reg 2-block cap without spilling).
// Wave w owns cols (g*8+w)*16+c0 for g=0..3 (Wf 96 VGPRs, held across all 12 periods).
// X B-frags read DIRECT from global (issued first, overlapped by H-part MFMAs).
// H single-buffered in LDS, pitch 130 bf16 = 65 dw (odd -> <=2-way banks, free).
// Epilogue: exp2/rcp forms (no fp division). bias/probs in LDS (transient regs only).
#define HS_P 130
__global__ __launch_bounds__(512, 2) void k_gate_all(const bf16_t* __restrict__ Xagg,
                                                     const bf16_t* __restrict__ WbT,
                                                     const float* __restrict__ bcomb,
                                                     const float* __restrict__ probs,
                                                     float* __restrict__ out, int N) {
  __shared__ bf16_t Hs[32][HS_P];
  __shared__ float biasS[512];
  __shared__ float probsS[16];
  const int tid = threadIdx.x;
  const int lane = tid & 63, w = tid >> 6;
  const int q = lane >> 4, c0 = lane & 15;
  const int n0 = blockIdx.x * 32;

  biasS[tid] = bcomb[tid];
  if (tid < PERIODSq) probsS[tid] = probs[tid];
  for (int i = tid; i < 32 * HS_P / 2; i += 512) ((unsigned int*)&Hs[0][0])[i] = 0u;

  // stationary W fragments: col = (g*8+w)*16 + c0, k-chunk ks*32 + q*8
  bf16x8 Wf[4][6];
#pragma unroll
  for (int g = 0; g < 4; ++g) {
    const bf16_t* wp = WbT + (size_t)((g * 8 + w) * 16 + c0) * 192;
#pragma unroll
    for (int ks = 0; ks < 6; ++ks) Wf[g][ks] = *(const bf16x8*)(wp + ks * 32 + q * 8);
  }
  floatx4 Cst[2], Ha[2];
#pragma unroll
  for (int rt = 0; rt < 2; ++rt) {
    Cst[rt] = (floatx4){0.f, 0.f, 0.f, 0.f};
    Ha[rt] = (floatx4){0.f, 0.f, 0.f, 0.f};
  }
  __syncthreads();

  const float NL2E = -1.44269504f;  // -log2(e)
  const float T2L2E = 2.88539008f;  // 2*log2(e)
  const bf16_t* Xrow0 = Xagg + (size_t)(n0 + c0) * 64 + q * 8;        // rt=0 node row
  const bf16_t* Xrow1 = Xagg + (size_t)(n0 + 16 + c0) * 64 + q * 8;   // rt=1 node row

  for (int t = 0; t < PERIODSq; ++t) {
    // X-part B-frags straight from global — long latency, overlapped by H-part MFMAs below
    const size_t toff = (size_t)t * N * 64;
    bf16x8 X00 = *(const bf16x8*)(Xrow0 + toff);
    bf16x8 X01 = *(const bf16x8*)(Xrow0 + toff + 32);
    bf16x8 X10 = *(const bf16x8*)(Xrow1 + toff);
    bf16x8 X11 = *(const bf16x8*)(Xrow1 + toff + 32);

    floatx4 acc[2][4];
#pragma unroll
    for (int rt = 0; rt < 2; ++rt)
#pragma unroll
      for (int g = 0; g < 4; ++g) acc[rt][g] = (floatx4){0.f, 0.f, 0.f, 0.f};

    // H-part (K = 64..191) from LDS
#pragma unroll
    for (int ks = 0; ks < 4; ++ks) {
      bf16x8 B0 = *(const bf16x8*)&Hs[c0][ks * 32 + q * 8];
      bf16x8 B1 = *(const bf16x8*)&Hs[16 + c0][ks * 32 + q * 8];
#pragma unroll
      for (int g = 0; g < 4; ++g) {
        acc[0][g] = __builtin_amdgcn_mfma_f32_16x16x32_bf16(Wf[g][ks + 2], B0, acc[0][g], 0, 0, 0);
        acc[1][g] = __builtin_amdgcn_mfma_f32_16x16x32_bf16(Wf[g][ks + 2], B1, acc[1][g], 0, 0, 0);
      }
    }
    // X-part (K = 0..63)
#pragma unroll
    for (int g = 0; g < 4; ++g) {
      acc[0][g] = __builtin_amdgcn_mfma_f32_16x16x32_bf16(Wf[g][0], X00, acc[0][g], 0, 0, 0);
      acc[1][g] = __builtin_amdgcn_mfma_f32_16x16x32_bf16(Wf[g][0], X10, acc[1][g], 0, 0, 0);
      acc[0][g] = __builtin_amdgcn_mfma_f32_16x16x32_bf16(Wf[g][1], X01, acc[0][g], 0, 0, 0);
      acc[1][g] = __builtin_amdgcn_mfma_f32_16x16x32_bf16(Wf[g][1], X11, acc[1][g], 0, 0, 0);
    }
    __syncthreads();  // all H reads done before overwrite

    const float pt = probsS[t];
#pragma unroll
    for (int rt = 0; rt < 2; ++rt) {
      bf16x4 hv;
#pragma unroll
      for (int r = 0; r < 4; ++r) {
        float pI = acc[rt][0][r] + biasS[0 + w * 16 + q * 4 + r];
        float pF = acc[rt][1][r] + biasS[128 + w * 16 + q * 4 + r];
        float pC = acc[rt][2][r] + biasS[256 + w * 16 + q * 4 + r];
        float pO = acc[rt][3][r] + biasS[384 + w * 16 + q * 4 + r];
        float I = __builtin_amdgcn_rcpf(1.0f + __builtin_amdgcn_exp2f(pI * NL2E));
        float F = __builtin_amdgcn_rcpf(1.0f + __builtin_amdgcn_exp2f(pF * NL2E));
        float Ct = fmaf(-2.0f, __builtin_amdgcn_rcpf(1.0f + __builtin_amdgcn_exp2f(pC * T2L2E)), 1.0f);
        float O = __builtin_amdgcn_rcpf(1.0f + __builtin_amdgcn_exp2f(pO * NL2E));
        float Cn = fmaf(F, Cst[rt][r], I * Ct);
        Cst[rt][r] = Cn;
        float tC = fmaf(-2.0f, __builtin_amdgcn_rcpf(1.0f + __builtin_amdgcn_exp2f(Cn * T2L2E)), 1.0f);
        float Hn = O * tC;
        Ha[rt][r] = fmaf(pt, Hn, Ha[rt][r]);
        hv[r] = (bf16_t)Hn;
      }
      *(bf16x4*)&Hs[rt * 16 + c0][w * 16 + q * 4] = hv;
    }
    __syncthreads();  // H(t+1) visible before next iteration's reads
  }
#pragma unroll
  for (int rt = 0; rt < 2; ++rt) {
    int row = n0 + rt * 16 + c0;
    *(floatx4*)(out + (size_t)row * 128 + w * 16 + q * 4) = Ha[rt];
  }
}

// ---------------- host ----------------
extern "C" void kernel_launch(void* const* d_in, const int* in_sizes, int n_in,
                              void* d_out, int out_size, void* d_ws, size_t ws_size,
                              hipStream_t stream) {
  const float* X = (const float*)d_in[0];
  const int* ei = (const int*)d_in[1];
  const float* ew = (const float*)d_in[2];
  const float* att = (const float*)d_in[3];
  const float* Wxi = (const float*)d_in[4];
  const float* bxi = (const float*)d_in[5];
  const float* Whi = (const float*)d_in[6];
  const float* bhi = (const float*)d_in[7];
  const float* Wxf = (const float*)d_in[8];
  const float* bxf = (const float*)d_in[9];
  const float* Whf = (const float*)d_in[10];
  const float* bhf = (const float*)d_in[11];
  const float* Wxc = (const float*)d_in[12];
  const float* bxc = (const float*)d_in[13];
  const float* Whc = (const float*)d_in[14];
  const float* bhc = (const float*)d_in[15];
  const float* Wxo = (const float*)d_in[16];
  const float* bxo = (const float*)d_in[17];
  const float* Who = (const float*)d_in[18];
  const float* bho = (const float*)d_in[19];
  float* out = (float*)d_out;

  const int N = in_sizes[0] / XROW;  // 40000
  const int E = in_sizes[2];         // 640000

  char* base = (char*)d_ws;
  size_t off = 0;
  auto carve = [&](size_t bytes) {
    char* r = base + off;
    off += (bytes + 255) & ~(size_t)255;
    return (void*)r;
  };
  float* deg = (float*)carve((size_t)N * 4);  // becomes dinv in-place
  int* counts = (int*)carve((size_t)N * 4);
  int* offs = (int*)carve((size_t)(N + 1) * 4);
  int* cursor = (int*)carve((size_t)(N + 1) * 4);
  int* csr_src = (int*)carve((size_t)E * 4);
  float* csr_nrm = (float*)carve((size_t)E * 4);
  bf16_t* WbT = (bf16_t*)carve((size_t)512 * 192 * 2);
  float* bcomb = (float*)carve(512 * 4);
  float* probs = (float*)carve(64);
  bf16_t* Xagg = (bf16_t*)carve((size_t)PERIODSq * N * 64 * 2);
  bf16_t* Xb = (bf16_t*)carve((size_t)N * XROW * 2);
  const bool use_bf16 = (off <= ws_size);  // fall back to fp32 gather if ws too small

  k_init<<<(N + 255) / 256, 256, 0, stream>>>(deg, counts, N);
  k_accum<<<(E + 255) / 256, 256, 0, stream>>>(ei, ew, deg, counts, E);
  k_dinv<<<(N + 255) / 256, 256, 0, stream>>>(deg, N);
  k_scan<<<1, 1024, 0, stream>>>(counts, offs, cursor, N);
  k_scatter<<<(E + 255) / 256, 256, 0, stream>>>(ei, ew, deg, cursor, csr_src, csr_nrm, E);
  k_prew<<<(512 * 192 + 512 + 1 + 255) / 256, 256, 0, stream>>>(
      Wxi, Whi, Wxf, Whf, Wxc, Whc, Wxo, Who,
      bxi, bhi, bxf, bhf, bxc, bhc, bxo, bho, att, WbT, bcomb, probs);

  if (use_bf16) {
    k_xpose<<<N, 192, 0, stream>>>(X, Xb);
    k_agg2<<<N / 4, 256, 0, stream>>>(Xb, csr_src, csr_nrm, offs, deg, Xagg, N);
  } else {
    k_agg<<<N, 256, 0, stream>>>(X, csr_src, csr_nrm, offs, deg, Xagg, N);
  }

  k_gate_all<<<N / 32, 512, 0, stream>>>(Xagg, WbT, bcomb, probs, out, N);
}